// Round 1
// 237.275 us; speedup vs baseline: 1.0042x; 1.0042x over previous
//
#include <hip/hip_runtime.h>

#define B_ 32
#define C_ 128
#define H_ 56
#define W_ 56
#define HW_ (H_*W_)            // 3136
#define SIZE_ (C_*HW_)         // 401408
#define NPIX_ (B_*HW_)         // 100352 = 784 * 128
#define HP_ 58
#define WP_ 58
#define PLANE_ (HP_*WP_*C_)    // 430592 bf16 elements per batch plane
#define K_ 1152                // 9 * 128
#define EPS_ 1e-5f
#define SLOPE_ 0.1f

typedef __bf16 bf16x8 __attribute__((ext_vector_type(8)));
typedef float  f32x4  __attribute__((ext_vector_type(4)));

__device__ __forceinline__ ushort f2bf(float x) {
    union { float f; unsigned u; } v; v.f = x;
    return (ushort)((v.u + 0x7FFFu + ((v.u >> 16) & 1u)) >> 16);   // RNE
}
__device__ __forceinline__ float lrelu(float z) { return z > 0.f ? z : SLOPE_ * z; }

// async global->LDS, 16B per lane; LDS dest = wave-uniform base + lane*16
__device__ __forceinline__ void glds16(const ushort* g, ushort* l) {
    __builtin_amdgcn_global_load_lds(
        (const __attribute__((address_space(1))) unsigned int*)g,
        (__attribute__((address_space(3))) unsigned int*)l, 16, 0, 0);
}

// ---------------------------------------------------------------------------
// prep: repack conv_w -> bf16 wA[co][k], k=(kh*3+kw)*128+ci; fold bias+BN2;
//       fold BN1 into per-position mix params p0,p1,p2.
// ---------------------------------------------------------------------------
__global__ __launch_bounds__(256) void prep_kernel(
    const float* __restrict__ conv_w, const float* __restrict__ conv_b,
    const float* __restrict__ g2, const float* __restrict__ b2,
    const float* __restrict__ m2, const float* __restrict__ v2,
    const float2* __restrict__ cfc, const float* __restrict__ g1,
    const float* __restrict__ b1, const float* __restrict__ mu1,
    const float* __restrict__ v1,
    ushort* __restrict__ wA, float* __restrict__ scale2, float* __restrict__ shift2,
    float* __restrict__ p0, float* __restrict__ p1, float* __restrict__ p2)
{
    int tid = blockIdx.x * 256 + threadIdx.x;
    if (tid < C_ * K_) {
        int co = tid / K_;
        int k  = tid - co * K_;
        int khkw = k >> 7, ci = k & 127;
        int kh = khkw / 3, kw = khkw - 3 * kh;
        wA[tid] = f2bf(conv_w[((co * C_ + ci) * 3 + kh) * 3 + kw]);
    }
    if (tid < C_) {
        float sc = g2[tid] * rsqrtf(v2[tid] + EPS_);
        scale2[tid] = sc;
        shift2[tid] = (conv_b[tid] - m2[tid]) * sc + b2[tid];
    }
    if (tid < SIZE_) {
        float sc = g1[tid] * rsqrtf(v1[tid] + EPS_);
        float2 wv = cfc[tid];
        p0[tid] = wv.x * sc;
        p1[tid] = wv.y * sc;
        p2[tid] = b1[tid] - mu1[tid] * sc;
    }
}

// ---------------------------------------------------------------------------
// zfuse: z = leaky(a*p0 + m*p1 + p2) -> bf16 NHWC zero-padded [32][58][58][128]
// one block per (b, padded row). float4 loads, LDS transpose (stride 132),
// uint2 coalesced write-out.
// ---------------------------------------------------------------------------
__global__ __launch_bounds__(256) void zfuse_kernel(
    const float4* __restrict__ ax, const float4* __restrict__ mx,
    const float4* __restrict__ p0, const float4* __restrict__ p1,
    const float4* __restrict__ p2, ushort* __restrict__ zp)
{
    __shared__ ushort tile[W_ * 132];   // stride 132: 8B-aligned rows, no 2^k banking
    const int hp = blockIdx.x, b = blockIdx.y;
    const int tid = threadIdx.x;
    ushort* row = zp + (size_t)b * PLANE_ + (size_t)hp * (WP_ * C_);
    if (hp == 0 || hp == HP_ - 1) {            // full zero border rows
        uint2* r2 = (uint2*)row;
        for (int i = tid; i < WP_ * C_ / 4; i += 256) r2[i] = make_uint2(0u, 0u);
        return;
    }
    const int h = hp - 1;
    const int base4 = (b * SIZE_) >> 2;
    for (int i = tid; i < 1792; i += 256) {    // 128 c * 14 float4-groups
        int c  = i / 14;
        int w4 = i - c * 14;
        int s4 = c * (HW_ / 4) + h * (W_ / 4) + w4;   // float4 index into [SIZE_]
        float4 a = ax[base4 + s4];
        float4 m = mx[base4 + s4];
        float4 q0 = p0[s4], q1 = p1[s4], q2 = p2[s4];
        int wb = w4 * 4;
        tile[(wb + 0) * 132 + c] = f2bf(lrelu(a.x * q0.x + m.x * q1.x + q2.x));
        tile[(wb + 1) * 132 + c] = f2bf(lrelu(a.y * q0.y + m.y * q1.y + q2.y));
        tile[(wb + 2) * 132 + c] = f2bf(lrelu(a.z * q0.z + m.z * q1.z + q2.z));
        tile[(wb + 3) * 132 + c] = f2bf(lrelu(a.w * q0.w + m.w * q1.w + q2.w));
    }
    __syncthreads();
    if (tid < C_) {                            // left/right border columns
        row[tid] = 0;
        row[(WP_ - 1) * C_ + tid] = 0;
    }
    for (int j = tid; j < 1792; j += 256) {    // 56 w * 32 uint2-chunks
        int w = j >> 5, cc = j & 31;
        *(uint2*)(row + C_ + w * C_ + cc * 4) = *(const uint2*)(tile + w * 132 + cc * 4);
    }
}

// ---------------------------------------------------------------------------
// conv: implicit GEMM, M=128co x N=100352px x K=1152, bf16 MFMA 16x16x32.
// 128x128 tile, BK=32, DOUBLE-buffered LDS (32KB), ONE barrier per K-step:
//   stage(step+1 -> buf^1) ; ds_read+MFMA(buf) ; __syncthreads (drains vmcnt)
// so global-load latency overlaps ds_read+MFMA instead of being exposed at a
// second barrier.  LDS XOR-swizzle (T2, via pre-swizzled GLOBAL source since
// global_load_lds dest must stay linear): chunk' = chunk ^ ((row>>1)&3),
// matching XOR on the read address -> 8-way bank conflict becomes 2-way (free).
// ---------------------------------------------------------------------------
__global__ __launch_bounds__(256) void conv_kernel(
    const ushort* __restrict__ zp, const ushort* __restrict__ wA,
    const float* __restrict__ scale2, const float* __restrict__ shift2,
    float* __restrict__ out)
{
    __shared__ ushort As[2][128 * 32];   // 2 x 8 KB: As[buf][co][32]
    __shared__ ushort Bs[2][128 * 32];   // 2 x 8 KB: Bs[buf][px][32]

    const int tid  = threadIdx.x;
    const int wave = tid >> 6, lane = tid & 63;
    const int l16  = lane & 15, quad = lane >> 4;
    const int pbase = blockIdx.x * 128;

    // ---- staging roles: each wave stages 32 rows (2 glds of 16 rows) ----
    const int srow = wave * 32 + (lane >> 2);     // LDS row for instr 0 (+16 for instr 1)
    const int skey = (srow >> 1) & 3;             // swizzle key; invariant under row+16
    const int sch  = (lane & 3) ^ skey;           // swizzled 16B source chunk in 64B row
    const ushort* agA = wA + srow * K_ + sch * 8; // A: weights (+16*K_ for instr 1)

    int pf0 = pbase + srow;
    int bb0 = pf0 / HW_, pi0 = pf0 - bb0 * HW_;
    int h0 = pi0 / W_, w0 = pi0 - h0 * W_;
    const ushort* bgB0 = zp + (size_t)bb0 * PLANE_ + (h0 * WP_ + w0) * C_ + sch * 8;
    int pf1 = pf0 + 16;
    int bb1 = pf1 / HW_, pi1 = pf1 - bb1 * HW_;
    int h1 = pi1 / W_, w1 = pi1 - h1 * W_;
    const ushort* bgB1 = zp + (size_t)bb1 * PLANE_ + (h1 * WP_ + w1) * C_ + sch * 8;

    const int lofs0 = (wave * 32) * 32;           // wave-uniform LDS dests (linear!)
    const int lofs1 = (wave * 32 + 16) * 32;

    // ---- compute roles: wave = 64co x 64px quadrant ----
    const int cob = (wave & 1) * 64;
    const int pxb = (wave >> 1) * 64;
    // read-side swizzle: key of row (cob/pxb + mt*16 + l16) reduces to (l16>>1)&3
    const int rquad = quad ^ ((l16 >> 1) & 3);

    f32x4 acc[4][4] = {};

#define STAGE(buf, aoff, boff)                                    \
    do {                                                          \
        glds16(agA + (aoff),           As[buf] + lofs0);          \
        glds16(agA + 16 * K_ + (aoff), As[buf] + lofs1);          \
        glds16(bgB0 + (boff),          Bs[buf] + lofs0);          \
        glds16(bgB1 + (boff),          Bs[buf] + lofs1);          \
    } while (0)

    // prologue: stage step 0 (tap 0, ks 0) into buf 0
    STAGE(0, 0, 0);
    __syncthreads();                              // drains vmcnt -> buf0 ready

    int zoff = 0, kw = 0;                         // current tap's zp offset
    for (int tap = 0; tap < 9; ++tap) {
        const int znext = (kw == 2) ? zoff + (WP_ - 2) * C_ : zoff + C_;
        #pragma unroll
        for (int ks = 0; ks < 4; ++ks) {
            const int buf  = ks & 1;              // steps/tap = 4 -> parity = ks&1
            const int step = tap * 4 + ks;
            // stage step+1 into the other buffer (A k-offset is just step*32)
            if (step < 35) {
                const int boffn = (ks < 3) ? zoff + (ks + 1) * 32 : znext;
                STAGE(buf ^ 1, (step + 1) * 32, boffn);
            }
            // ds_read current buffer (swizzled chunk), then MFMA
            bf16x8 af[4], bfr[4];
            #pragma unroll
            for (int mt = 0; mt < 4; ++mt)
                af[mt] = *(const bf16x8*)(As[buf] + (cob + mt * 16 + l16) * 32 + rquad * 8);
            #pragma unroll
            for (int nt = 0; nt < 4; ++nt)
                bfr[nt] = *(const bf16x8*)(Bs[buf] + (pxb + nt * 16 + l16) * 32 + rquad * 8);
            #pragma unroll
            for (int mt = 0; mt < 4; ++mt)
                #pragma unroll
                for (int nt = 0; nt < 4; ++nt)
                    acc[mt][nt] = __builtin_amdgcn_mfma_f32_16x16x32_bf16(
                        af[mt], bfr[nt], acc[mt][nt], 0, 0, 0);
            // ONE barrier per step: drains this step's stage (vmcnt0 at barrier)
            // and guarantees all waves done reading buf before it is re-staged.
            __syncthreads();
        }
        zoff = znext;
        if (kw == 2) kw = 0; else ++kw;
    }
#undef STAGE

    // ---- epilogue: fused scale/shift + leaky, NCHW fp32 stores ----
    int pob[4];
    #pragma unroll
    for (int nt = 0; nt < 4; ++nt) {
        int pf = pbase + pxb + nt * 16 + l16;
        int bb = pf / HW_;
        pob[nt] = bb * SIZE_ + (pf - bb * HW_);
    }
    #pragma unroll
    for (int mt = 0; mt < 4; ++mt) {
        #pragma unroll
        for (int r = 0; r < 4; ++r) {
            int co = cob + mt * 16 + quad * 4 + r;
            float sc = scale2[co], sh = shift2[co];
            #pragma unroll
            for (int nt = 0; nt < 4; ++nt) {
                float v = acc[mt][nt][r] * sc + sh;
                out[(size_t)pob[nt] + co * HW_] = lrelu(v);
            }
        }
    }
}

// ---------------------------------------------------------------------------
extern "C" void kernel_launch(void* const* d_in, const int* in_sizes, int n_in,
                              void* d_out, int out_size, void* d_ws, size_t ws_size,
                              hipStream_t stream) {
    const float* ax     = (const float*)d_in[0];
    const float* mx     = (const float*)d_in[1];
    const float* cfc    = (const float*)d_in[2];
    const float* bn_g   = (const float*)d_in[3];
    const float* bn_b   = (const float*)d_in[4];
    const float* bn_m   = (const float*)d_in[5];
    const float* bn_v   = (const float*)d_in[6];
    const float* conv_w = (const float*)d_in[7];
    const float* conv_b = (const float*)d_in[8];
    const float* g2     = (const float*)d_in[9];
    const float* b2     = (const float*)d_in[10];
    const float* m2     = (const float*)d_in[11];
    const float* v2     = (const float*)d_in[12];
    float* out = (float*)d_out;

    char* ws = (char*)d_ws;
    // zp: 27,557,888 B | wA: 294,912 B | scale2/shift2: 512 B each | p0/p1/p2: 1,605,632 B each
    ushort* zp     = (ushort*)ws;
    ushort* wA     = (ushort*)(ws + 27557888);
    float*  scale2 = (float*)(ws + 27852800);
    float*  shift2 = (float*)(ws + 27853312);
    float*  p0     = (float*)(ws + 27853824);
    float*  p1     = (float*)(ws + 29459456);
    float*  p2     = (float*)(ws + 31065088);

    prep_kernel<<<dim3((SIZE_ + 255) / 256), 256, 0, stream>>>(
        conv_w, conv_b, g2, b2, m2, v2, (const float2*)cfc,
        bn_g, bn_b, bn_m, bn_v, wA, scale2, shift2, p0, p1, p2);
    zfuse_kernel<<<dim3(HP_, B_), 256, 0, stream>>>(
        (const float4*)ax, (const float4*)mx,
        (const float4*)p0, (const float4*)p1, (const float4*)p2, zp);
    conv_kernel<<<dim3(NPIX_ / 128), 256, 0, stream>>>(zp, wA, scale2, shift2, out);
}